// Round 9
// baseline (147.021 us; speedup 1.0000x reference)
//
#include <hip/hip_runtime.h>

#define IMG_W 512
#define IMG_H 512
#define PLANE_PX (IMG_W * IMG_H)
#define N_ELEMS (48 * PLANE_PX)
#define NT 256
#define BX 128                  // out cols per block
#define NTILE 9                 // 9 staged 16-col tiles = 144 cols (128 + 2x8 halo)
#define PSTR 152                // shorts per LDS plane row (bank-optimal stride)
#define PPL (16 * PSTR)         // shorts per plane = 2432
#define NBLK (48 * 32 * 4)      // 6144 blocks

// 2*C1 and 2*C2 (the 0.25 scale factors cancel in num/den)
#define C1x2 2.0e-4f
#define C2x2 1.8e-3f

typedef _Float16 h2 __attribute__((ext_vector_type(2)));
typedef _Float16 h8 __attribute__((ext_vector_type(8)));
typedef float f32x2 __attribute__((ext_vector_type(2)));
typedef float f32x4 __attribute__((ext_vector_type(4)));
typedef __fp16 fp16v2 __attribute__((ext_vector_type(2)));

__device__ __forceinline__ unsigned int h2bits(h2 v) {
    union { h2 h; unsigned int u; } c; c.h = v; return c.u;
}
// v_cvt_pkrtz_f16_f32 returns __fp16x2; bit-cast to _Float16x2 (same layout).
__device__ __forceinline__ h2 pkrtz(float x, float y) {
    union { fp16v2 f; h2 h; } c;
    c.f = __builtin_amdgcn_cvt_pkrtz(x, y);
    return c.h;
}

union FrU { h8 h; unsigned u[4]; h2 p[4]; };

__global__ void __launch_bounds__(NT, 8) ssim_main(
    const float* __restrict__ img1, const float* __restrict__ img2,
    float* __restrict__ partials)
{
    // BOTH convs on MFMA + 100%-occupancy-cap config:
    // block = 128 out cols x 16 rows, 256 threads (4 waves), LDS 19.4 KB
    // -> 8 blocks/CU = 2048 threads (the R5 regime that achieved 63% occ),
    // with ~28 inst/px (vs R5's ~59).
    // Phase A (vertical, R2-verified layout): mfma(A=signal, B=afv);
    //   A[m][k]: m = staged col in 16-tile (lane&15), k = row slot khi*8+j;
    //   D: row khi*4+i = staged col, col lane&15 = out row -> 4 f16 packed
    //   to ONE ds_write_b64 per plane. f32 accumulation (better than pk_fma).
    // Result: 4 SEPARATE f16 planes S,D,SS,DD [16 rows][152 cols] -> Phase B
    //   B-fragment = ONE ds_read_b128 per plane, ZERO de-interleave perms.
    // Stride 152 (304 B/row): row-starts tile all 32 banks uniformly ->
    //   b128 reads and b64 writes at exact bank minimum.
    __shared__ __align__(16) unsigned short P[4 * PPL];   // 19,456 B

    const int tid = threadIdx.x;
    const int lane = tid & 63;
    const int wv = tid >> 6;                     // wave [0,4)
    const int nr = lane & 15;
    const int khi = lane >> 4;

    // Work decode + XCD swizzle: XCD (blockIdx&7) owns 6 contiguous planes.
    const int xcd = blockIdx.x & 7;
    const int idx = blockIdx.x >> 3;             // [0,768)
    const int pl = xcd * 6 + (idx >> 7);         // 128 blocks/plane
    const int rem = idx & 127;
    const int band = rem >> 2;                   // [0,32) -> 16-row band
    const int cb = rem & 3;                      // [0,4)  -> 128-col block
    const int bx0 = cb * BX;
    const int ty0 = band * 16;
    const float* pa = img1 + (size_t)pl * PLANE_PX;
    const float* pb = img2 + (size_t)pl * PLANE_PX;

    // Gaussian band fragments (lanes >= 11 hold 0):
    //   afv (vertical B):   B[k][n] = G[k-n]   (k row slot, n out row)
    //   afh (horizontal A): A[m][k] = G[k-m-3] (staged window base = out-8)
    int sidx = min(lane, 10 - lane);             // < 0 for lane > 10
    unsigned gvb = 0u;
    gvb = (sidx == 0) ? 0x1436u : gvb;           // f16 bits of G[0]
    gvb = (sidx == 1) ? 0x1FC8u : gvb;
    gvb = (sidx == 2) ? 0x289Cu : gvb;
    gvb = (sidx == 3) ? 0x2F00u : gvb;
    gvb = (sidx == 4) ? 0x32D1u : gvb;
    gvb = (sidx == 5) ? 0x3442u : gvb;           // f16 bits of G[5]
    FrU afv, afh;
#pragma unroll
    for (int w = 0; w < 4; ++w) {
        int t0 = khi * 8 + 2 * w - nr;
        unsigned lo = (unsigned)__shfl((int)gvb, t0 & 63, 64);
        unsigned hi = (unsigned)__shfl((int)gvb, (t0 + 1) & 63, 64);
        afv.u[w] = (lo & 0xFFFFu) | (hi << 16);
        unsigned lo2 = (unsigned)__shfl((int)gvb, (t0 - 3) & 63, 64);
        unsigned hi2 = (unsigned)__shfl((int)gvb, (t0 - 2) & 63, 64);
        afh.u[w] = (lo2 & 0xFFFFu) | (hi2 << 16);
    }

    const f32x4 z = {0.f, 0.f, 0.f, 0.f};

    // ================= Phase A: vertical conv via MFMA ======================
    // Staged rows: k = khi*8+j; slots k >= 26 have G[k-n]=0 (n<=15), their
    // loaded values are clamped-finite and contribute nothing.
    const int ryb = ty0 - 5 + khi * 8;
    const bool fastY = (ty0 >= 16) && (ty0 <= 480);          // bands 1..30
    const bool eb = (cb == 0) || (cb == 3);                  // edge col-blocks

    for (int tt = wv; tt < NTILE; tt += 4) {     // waves: {3,2,2,2} tiles
        const int gx = bx0 - 8 + tt * 16 + nr;   // per-lane staged col
        const int cgx = min(max(gx, 0), IMG_W - 1);
        float a[8], b[8];
        if (fastY) {
            const float* qa = pa + (size_t)ryb * IMG_W + cgx;
            const float* qb = pb + (size_t)ryb * IMG_W + cgx;
#pragma unroll
            for (int j = 0; j < 8; ++j) {
                a[j] = qa[j * IMG_W];
                b[j] = qb[j * IMG_W];
            }
        } else {
#pragma unroll
            for (int j = 0; j < 8; ++j) {
                int ry = ryb + j;
                int ryc = min(max(ry, 0), IMG_H - 1);
                float rm = ((unsigned)ry < (unsigned)IMG_H) ? 1.f : 0.f;
                a[j] = pa[(size_t)ryc * IMG_W + cgx] * rm;
                b[j] = pb[(size_t)ryc * IMG_W + cgx] * rm;
            }
        }
        FrU FS, FD, FSS, FDD;
#pragma unroll
        for (int w = 0; w < 4; ++w) {
            FS.p[w] = pkrtz(a[2 * w] + b[2 * w], a[2 * w + 1] + b[2 * w + 1]);
            FD.p[w] = pkrtz(a[2 * w] - b[2 * w], a[2 * w + 1] - b[2 * w + 1]);
        }
        if (eb) {   // zero OOB columns (horizontal zero-pad semantics)
            const _Float16 ml = ((unsigned)gx < (unsigned)IMG_W)
                                    ? (_Float16)1.f : (_Float16)0.f;
            const h2 mlv = {ml, ml};
#pragma unroll
            for (int w = 0; w < 4; ++w) { FS.p[w] *= mlv; FD.p[w] *= mlv; }
        }
#pragma unroll
        for (int w = 0; w < 4; ++w) {
            FSS.p[w] = FS.p[w] * FS.p[w];        // v_pk_mul_f16
            FDD.p[w] = FD.p[w] * FD.p[w];
        }
        f32x4 oS  = __builtin_amdgcn_mfma_f32_16x16x32_f16(FS.h,  afv.h, z, 0, 0, 0);
        f32x4 oD  = __builtin_amdgcn_mfma_f32_16x16x32_f16(FD.h,  afv.h, z, 0, 0, 0);
        f32x4 oSS = __builtin_amdgcn_mfma_f32_16x16x32_f16(FSS.h, afv.h, z, 0, 0, 0);
        f32x4 oDD = __builtin_amdgcn_mfma_f32_16x16x32_f16(FDD.h, afv.h, z, 0, 0, 0);

        // D: thread holds staged cols tt*16 + khi*4 .. +3 at out row nr.
        const int wco = nr * PSTR + tt * 16 + khi * 4;       // shorts, 8B-align
        *(uint2*)&P[0 * PPL + wco] = make_uint2(h2bits(pkrtz(oS[0],  oS[1])),
                                                h2bits(pkrtz(oS[2],  oS[3])));
        *(uint2*)&P[1 * PPL + wco] = make_uint2(h2bits(pkrtz(oD[0],  oD[1])),
                                                h2bits(pkrtz(oD[2],  oD[3])));
        *(uint2*)&P[2 * PPL + wco] = make_uint2(h2bits(pkrtz(oSS[0], oSS[1])),
                                                h2bits(pkrtz(oSS[2], oSS[3])));
        *(uint2*)&P[3 * PPL + wco] = make_uint2(h2bits(pkrtz(oDD[0], oDD[1])),
                                                h2bits(pkrtz(oDD[2], oDD[3])));
    }
    __syncthreads();

    // ================= Phase B: horizontal conv via MFMA + SSIM =============
    // mfma(A = afh, B = plane): B[k][n]: n = row (lane&15), k = staged col
    // (khi*8+j) -> ONE ds_read_b128 per plane. D: r = khi*4+i = out col,
    // c = lane&15 = row. All outputs valid (zero-pad handled in Phase A).
    f32x2 acc2 = {0.f, 0.f};
    const f32x2 c1v = {C1x2, C1x2};
    const f32x2 c2v = {C2x2, C2x2};
#pragma unroll
    for (int g2 = 0; g2 < 2; ++g2) {
        const int og = wv * 2 + g2;              // out-col group [0,8)
        const int ko = nr * PSTR + og * 16 + khi * 8;        // shorts, 16B-align
        h8 fS  = *(const h8*)&P[0 * PPL + ko];
        h8 fD  = *(const h8*)&P[1 * PPL + ko];
        h8 fSS = *(const h8*)&P[2 * PPL + ko];
        h8 fDD = *(const h8*)&P[3 * PPL + ko];
        f32x4 aS  = __builtin_amdgcn_mfma_f32_16x16x32_f16(afh.h, fS,  z, 0, 0, 0);
        f32x4 aD  = __builtin_amdgcn_mfma_f32_16x16x32_f16(afh.h, fD,  z, 0, 0, 0);
        f32x4 aSS = __builtin_amdgcn_mfma_f32_16x16x32_f16(afh.h, fSS, z, 0, 0, 0);
        f32x4 aDD = __builtin_amdgcn_mfma_f32_16x16x32_f16(afh.h, fDD, z, 0, 0, 0);

        // SSIM epilogue, packed f32 (v_pk_{mul,add,fma}_f32): 2 px/inst.
        // num/den share the 0.25 factor -> cancelled; constants are 2*C.
#pragma unroll
        for (int h = 0; h < 2; ++h) {
            f32x2 cs  = {aS[2 * h],  aS[2 * h + 1]};
            f32x2 cd  = {aD[2 * h],  aD[2 * h + 1]};
            f32x2 css = {aSS[2 * h], aSS[2 * h + 1]};
            f32x2 cdd = {aDD[2 * h], aDD[2 * h + 1]};
            f32x2 Pq = cs * cs, Qq = cd * cd;
            f32x2 U = Pq - Qq;                   // 4*mu1*mu2
            f32x2 V = Pq + Qq;                   // 2*(mu1^2+mu2^2)
            f32x2 num = (U + c1v) * ((css - cdd) - U + c2v);
            f32x2 den = (V + c1v) * ((css + cdd) - V + c2v);
            f32x2 rr = {__builtin_amdgcn_rcpf(den.x),
                        __builtin_amdgcn_rcpf(den.y)};
            acc2 = __builtin_elementwise_fma(num, rr, acc2);
        }
    }
    float local = acc2.x + acc2.y;

    // ================= Block reduction -> one partial ========================
#pragma unroll
    for (int off = 32; off > 0; off >>= 1) local += __shfl_down(local, off, 64);
    __syncthreads();                             // all P reads done: safe alias
    float* wp = (float*)P;
    if (lane == 0) wp[wv] = local;
    __syncthreads();
    if (tid == 0)
        partials[blockIdx.x] = wp[0] + wp[1] + wp[2] + wp[3];
}

__global__ void ssim_final(const float* __restrict__ partials,
                           float* __restrict__ out)
{
    __shared__ float wp[4];
    const int tid = threadIdx.x;
    const float4* p4 = (const float4*)partials;  // 6144/4 = 1536 float4
    float s = 0.f;
    for (int i = tid; i < NBLK / 4; i += NT) {
        float4 v = p4[i];
        s += (v.x + v.y) + (v.z + v.w);
    }
#pragma unroll
    for (int off = 32; off > 0; off >>= 1) s += __shfl_down(s, off, 64);
    if ((tid & 63) == 0) wp[tid >> 6] = s;
    __syncthreads();
    if (tid == 0)
        out[0] = 1.0f - (wp[0] + wp[1] + wp[2] + wp[3]) * (1.0f / (float)N_ELEMS);
}

extern "C" void kernel_launch(void* const* d_in, const int* in_sizes, int n_in,
                              void* d_out, int out_size, void* d_ws, size_t ws_size,
                              hipStream_t stream) {
    const float* img1 = (const float*)d_in[0];
    const float* img2 = (const float*)d_in[1];
    float* out = (float*)d_out;
    float* partials = (float*)d_ws;     // NBLK floats = 24.6 KB

    ssim_main<<<NBLK, NT, 0, stream>>>(img1, img2, partials);
    ssim_final<<<1, NT, 0, stream>>>(partials, out);
}

// Round 10
// 138.090 us; speedup vs baseline: 1.0647x; 1.0647x over previous
//
#include <hip/hip_runtime.h>

#define IMG_W 512
#define IMG_H 512
#define PLANE_PX (IMG_W * IMG_H)
#define N_ELEMS (48 * PLANE_PX)
#define NT 256
#define BX 128                  // out cols per block
#define NTILE 9                 // 9 staged 16-col tiles = 144 cols (128 + 2x8 halo)
#define PSTR 152                // shorts per LDS plane row (bank-optimal stride)
#define PPL (16 * PSTR)         // shorts per plane = 2432
#define NBLK (48 * 32 * 4)      // 6144 blocks

// 2*C1 and 2*C2 (the 0.25 scale factors cancel in num/den)
#define C1x2 2.0e-4f
#define C2x2 1.8e-3f

typedef _Float16 h2 __attribute__((ext_vector_type(2)));
typedef _Float16 h8 __attribute__((ext_vector_type(8)));
typedef float f32x2 __attribute__((ext_vector_type(2)));
typedef float f32x4 __attribute__((ext_vector_type(4)));
typedef __fp16 fp16v2 __attribute__((ext_vector_type(2)));

__device__ __forceinline__ unsigned int h2bits(h2 v) {
    union { h2 h; unsigned int u; } c; c.h = v; return c.u;
}
// v_cvt_pkrtz_f16_f32 returns __fp16x2; bit-cast to _Float16x2 (same layout).
__device__ __forceinline__ h2 pkrtz(float x, float y) {
    union { fp16v2 f; h2 h; } c;
    c.f = __builtin_amdgcn_cvt_pkrtz(x, y);
    return c.h;
}

union FrU { h8 h; unsigned u[4]; h2 p[4]; };

__global__ void __launch_bounds__(NT, 6) ssim_main(
    const float* __restrict__ img1, const float* __restrict__ img2,
    float* __restrict__ partials)
{
    // R9 design (both convs on MFMA, ~24 inst/px, passed correctness) with
    // the spill fixed: launch_bounds (256,6) -> 85 VGPR/wave (R9's (256,8)
    // = 64 incl. MFMA accumulators -> 18.6 MB scratch traffic, the entire
    // 56us regression). Cap: 6 blocks/CU = 75% thread occupancy.
    // Phase A (vertical, verified layout): mfma(A=signal, B=afv);
    //   A[m][k]: m = staged col in 16-tile (lane&15), k = row slot khi*8+j;
    //   D: row khi*4+i = staged col, col lane&15 = out row -> 4 f16 packed
    //   to ONE ds_write_b64 per plane. f32 accumulation.
    // 4 SEPARATE f16 planes S,D,SS,DD [16 rows][152 cols] -> Phase B
    //   B-fragment = ONE ds_read_b128 per plane, zero de-interleave perms.
    // Stride 152 (304 B/row): b128 reads / b64 writes at exact bank minimum.
    __shared__ __align__(16) unsigned short P[4 * PPL];   // 19,456 B

    const int tid = threadIdx.x;
    const int lane = tid & 63;
    const int wv = tid >> 6;                     // wave [0,4)
    const int nr = lane & 15;
    const int khi = lane >> 4;

    // Work decode + XCD swizzle: XCD (blockIdx&7) owns 6 contiguous planes.
    const int xcd = blockIdx.x & 7;
    const int idx = blockIdx.x >> 3;             // [0,768)
    const int pl = xcd * 6 + (idx >> 7);         // 128 blocks/plane
    const int rem = idx & 127;
    const int band = rem >> 2;                   // [0,32) -> 16-row band
    const int cb = rem & 3;                      // [0,4)  -> 128-col block
    const int bx0 = cb * BX;
    const int ty0 = band * 16;
    const float* pa = img1 + (size_t)pl * PLANE_PX;
    const float* pb = img2 + (size_t)pl * PLANE_PX;

    // Gaussian band fragments (lanes >= 11 hold 0):
    //   afv (vertical B):   B[k][n] = G[k-n]   (k row slot, n out row)
    //   afh (horizontal A): A[m][k] = G[k-m-3] (staged window base = out-8)
    int sidx = min(lane, 10 - lane);             // < 0 for lane > 10
    unsigned gvb = 0u;
    gvb = (sidx == 0) ? 0x1436u : gvb;           // f16 bits of G[0]
    gvb = (sidx == 1) ? 0x1FC8u : gvb;
    gvb = (sidx == 2) ? 0x289Cu : gvb;
    gvb = (sidx == 3) ? 0x2F00u : gvb;
    gvb = (sidx == 4) ? 0x32D1u : gvb;
    gvb = (sidx == 5) ? 0x3442u : gvb;           // f16 bits of G[5]
    FrU afv, afh;
#pragma unroll
    for (int w = 0; w < 4; ++w) {
        int t0 = khi * 8 + 2 * w - nr;
        unsigned lo = (unsigned)__shfl((int)gvb, t0 & 63, 64);
        unsigned hi = (unsigned)__shfl((int)gvb, (t0 + 1) & 63, 64);
        afv.u[w] = (lo & 0xFFFFu) | (hi << 16);
        unsigned lo2 = (unsigned)__shfl((int)gvb, (t0 - 3) & 63, 64);
        unsigned hi2 = (unsigned)__shfl((int)gvb, (t0 - 2) & 63, 64);
        afh.u[w] = (lo2 & 0xFFFFu) | (hi2 << 16);
    }

    const f32x4 z = {0.f, 0.f, 0.f, 0.f};

    // ================= Phase A: vertical conv via MFMA ======================
    // Staged rows: k = khi*8+j; slots k >= 26 have G[k-n]=0 (n<=15), their
    // loaded values are clamped-finite and contribute nothing.
    const int ryb = ty0 - 5 + khi * 8;
    const bool fastY = (ty0 >= 16) && (ty0 <= 480);          // bands 1..30
    const bool eb = (cb == 0) || (cb == 3);                  // edge col-blocks

    for (int tt = wv; tt < NTILE; tt += 4) {     // waves: {3,2,2,2} tiles
        const int gx = bx0 - 8 + tt * 16 + nr;   // per-lane staged col
        const int cgx = min(max(gx, 0), IMG_W - 1);
        float a[8], b[8];
        if (fastY) {
            const float* qa = pa + (size_t)ryb * IMG_W + cgx;
            const float* qb = pb + (size_t)ryb * IMG_W + cgx;
#pragma unroll
            for (int j = 0; j < 8; ++j) {
                a[j] = qa[j * IMG_W];
                b[j] = qb[j * IMG_W];
            }
        } else {
#pragma unroll
            for (int j = 0; j < 8; ++j) {
                int ry = ryb + j;
                int ryc = min(max(ry, 0), IMG_H - 1);
                float rm = ((unsigned)ry < (unsigned)IMG_H) ? 1.f : 0.f;
                a[j] = pa[(size_t)ryc * IMG_W + cgx] * rm;
                b[j] = pb[(size_t)ryc * IMG_W + cgx] * rm;
            }
        }
        FrU FS, FD, FSS, FDD;
#pragma unroll
        for (int w = 0; w < 4; ++w) {
            FS.p[w] = pkrtz(a[2 * w] + b[2 * w], a[2 * w + 1] + b[2 * w + 1]);
            FD.p[w] = pkrtz(a[2 * w] - b[2 * w], a[2 * w + 1] - b[2 * w + 1]);
        }
        if (eb) {   // zero OOB columns (horizontal zero-pad semantics)
            const _Float16 ml = ((unsigned)gx < (unsigned)IMG_W)
                                    ? (_Float16)1.f : (_Float16)0.f;
            const h2 mlv = {ml, ml};
#pragma unroll
            for (int w = 0; w < 4; ++w) { FS.p[w] *= mlv; FD.p[w] *= mlv; }
        }
#pragma unroll
        for (int w = 0; w < 4; ++w) {
            FSS.p[w] = FS.p[w] * FS.p[w];        // v_pk_mul_f16
            FDD.p[w] = FD.p[w] * FD.p[w];
        }
        f32x4 oS  = __builtin_amdgcn_mfma_f32_16x16x32_f16(FS.h,  afv.h, z, 0, 0, 0);
        f32x4 oD  = __builtin_amdgcn_mfma_f32_16x16x32_f16(FD.h,  afv.h, z, 0, 0, 0);
        f32x4 oSS = __builtin_amdgcn_mfma_f32_16x16x32_f16(FSS.h, afv.h, z, 0, 0, 0);
        f32x4 oDD = __builtin_amdgcn_mfma_f32_16x16x32_f16(FDD.h, afv.h, z, 0, 0, 0);

        // D: thread holds staged cols tt*16 + khi*4 .. +3 at out row nr.
        const int wco = nr * PSTR + tt * 16 + khi * 4;       // shorts, 8B-align
        *(uint2*)&P[0 * PPL + wco] = make_uint2(h2bits(pkrtz(oS[0],  oS[1])),
                                                h2bits(pkrtz(oS[2],  oS[3])));
        *(uint2*)&P[1 * PPL + wco] = make_uint2(h2bits(pkrtz(oD[0],  oD[1])),
                                                h2bits(pkrtz(oD[2],  oD[3])));
        *(uint2*)&P[2 * PPL + wco] = make_uint2(h2bits(pkrtz(oSS[0], oSS[1])),
                                                h2bits(pkrtz(oSS[2], oSS[3])));
        *(uint2*)&P[3 * PPL + wco] = make_uint2(h2bits(pkrtz(oDD[0], oDD[1])),
                                                h2bits(pkrtz(oDD[2], oDD[3])));
    }
    __syncthreads();

    // ================= Phase B: horizontal conv via MFMA + SSIM =============
    // mfma(A = afh, B = plane): B[k][n]: n = row (lane&15), k = staged col
    // (khi*8+j) -> ONE ds_read_b128 per plane. D: r = khi*4+i = out col,
    // c = lane&15 = row. All outputs valid (zero-pad handled in Phase A).
    f32x2 acc2 = {0.f, 0.f};
    const f32x2 c1v = {C1x2, C1x2};
    const f32x2 c2v = {C2x2, C2x2};
#pragma unroll
    for (int g2 = 0; g2 < 2; ++g2) {
        const int og = wv * 2 + g2;              // out-col group [0,8)
        const int ko = nr * PSTR + og * 16 + khi * 8;        // shorts, 16B-align
        h8 fS  = *(const h8*)&P[0 * PPL + ko];
        h8 fD  = *(const h8*)&P[1 * PPL + ko];
        h8 fSS = *(const h8*)&P[2 * PPL + ko];
        h8 fDD = *(const h8*)&P[3 * PPL + ko];
        f32x4 aS  = __builtin_amdgcn_mfma_f32_16x16x32_f16(afh.h, fS,  z, 0, 0, 0);
        f32x4 aD  = __builtin_amdgcn_mfma_f32_16x16x32_f16(afh.h, fD,  z, 0, 0, 0);
        f32x4 aSS = __builtin_amdgcn_mfma_f32_16x16x32_f16(afh.h, fSS, z, 0, 0, 0);
        f32x4 aDD = __builtin_amdgcn_mfma_f32_16x16x32_f16(afh.h, fDD, z, 0, 0, 0);

        // SSIM epilogue, packed f32 (v_pk_{mul,add,fma}_f32): 2 px/inst.
        // num/den share the 0.25 factor -> cancelled; constants are 2*C.
#pragma unroll
        for (int h = 0; h < 2; ++h) {
            f32x2 cs  = {aS[2 * h],  aS[2 * h + 1]};
            f32x2 cd  = {aD[2 * h],  aD[2 * h + 1]};
            f32x2 css = {aSS[2 * h], aSS[2 * h + 1]};
            f32x2 cdd = {aDD[2 * h], aDD[2 * h + 1]};
            f32x2 Pq = cs * cs, Qq = cd * cd;
            f32x2 U = Pq - Qq;                   // 4*mu1*mu2
            f32x2 V = Pq + Qq;                   // 2*(mu1^2+mu2^2)
            f32x2 num = (U + c1v) * ((css - cdd) - U + c2v);
            f32x2 den = (V + c1v) * ((css + cdd) - V + c2v);
            f32x2 rr = {__builtin_amdgcn_rcpf(den.x),
                        __builtin_amdgcn_rcpf(den.y)};
            acc2 = __builtin_elementwise_fma(num, rr, acc2);
        }
    }
    float local = acc2.x + acc2.y;

    // ================= Block reduction -> one partial ========================
#pragma unroll
    for (int off = 32; off > 0; off >>= 1) local += __shfl_down(local, off, 64);
    __syncthreads();                             // all P reads done: safe alias
    float* wp = (float*)P;
    if (lane == 0) wp[wv] = local;
    __syncthreads();
    if (tid == 0)
        partials[blockIdx.x] = wp[0] + wp[1] + wp[2] + wp[3];
}

__global__ void ssim_final(const float* __restrict__ partials,
                           float* __restrict__ out)
{
    __shared__ float wp[4];
    const int tid = threadIdx.x;
    const float4* p4 = (const float4*)partials;  // 6144/4 = 1536 float4
    float s = 0.f;
    for (int i = tid; i < NBLK / 4; i += NT) {
        float4 v = p4[i];
        s += (v.x + v.y) + (v.z + v.w);
    }
#pragma unroll
    for (int off = 32; off > 0; off >>= 1) s += __shfl_down(s, off, 64);
    if ((tid & 63) == 0) wp[tid >> 6] = s;
    __syncthreads();
    if (tid == 0)
        out[0] = 1.0f - (wp[0] + wp[1] + wp[2] + wp[3]) * (1.0f / (float)N_ELEMS);
}

extern "C" void kernel_launch(void* const* d_in, const int* in_sizes, int n_in,
                              void* d_out, int out_size, void* d_ws, size_t ws_size,
                              hipStream_t stream) {
    const float* img1 = (const float*)d_in[0];
    const float* img2 = (const float*)d_in[1];
    float* out = (float*)d_out;
    float* partials = (float*)d_ws;     // NBLK floats = 24.6 KB

    ssim_main<<<NBLK, NT, 0, stream>>>(img1, img2, partials);
    ssim_final<<<1, NT, 0, stream>>>(partials, out);
}